// Round 2
// baseline (667.277 us; speedup 1.0000x reference)
//
#include <hip/hip_runtime.h>
#include <hip/hip_bf16.h>

#define NPTS 40000
#define KNBR 32
#define CDIM 256
#define NH 8
#define HD 32

static constexpr float QK_SCALE = 0.17677669529663687f; // 32^-0.5

// ---------------- Kernel 1: fused QKV projection with sort-gather ----------------
// grid = NPTS/32 blocks, 256 threads. Block computes 32 sorted rows x 256 cols x {q,k,v}.
// q written fp32 (scale folded); k,v written interleaved bf16 pairs for the attn gather.
__global__ __launch_bounds__(256, 2) void qkv_kernel(
    const float* __restrict__ qf,
    const float* __restrict__ Wq, const float* __restrict__ bq,
    const float* __restrict__ Wk, const float* __restrict__ bk,
    const float* __restrict__ Wv, const float* __restrict__ bv,
    const int* __restrict__ sort_idx,
    float* __restrict__ qs, __hip_bfloat162* __restrict__ kvs)
{
    __shared__ float in_t[CDIM][40];
    const int t = threadIdx.x;
    const int row0 = blockIdx.x * 32;

    #pragma unroll 8
    for (int r = 0; r < 32; ++r) {
        int src = sort_idx[row0 + r];          // uniform -> scalar load
        in_t[t][r] = qf[src * CDIM + t];       // coalesced 1KB row load
    }
    __syncthreads();

    float accq[32], acck[32], accv[32];
    #pragma unroll
    for (int r = 0; r < 32; ++r) { accq[r] = 0.f; acck[r] = 0.f; accv[r] = 0.f; }

    #pragma unroll 2
    for (int c = 0; c < CDIM; ++c) {
        float wq = Wq[c * CDIM + t];           // coalesced, L2-hot (256KB each)
        float wk = Wk[c * CDIM + t];
        float wv = Wv[c * CDIM + t];
        #pragma unroll
        for (int r4 = 0; r4 < 8; ++r4) {
            const float4 a = *reinterpret_cast<const float4*>(&in_t[c][r4 * 4]); // wave-broadcast
            const float av[4] = {a.x, a.y, a.z, a.w};
            #pragma unroll
            for (int i = 0; i < 4; ++i) {
                accq[r4 * 4 + i] = fmaf(av[i], wq, accq[r4 * 4 + i]);
                acck[r4 * 4 + i] = fmaf(av[i], wk, acck[r4 * 4 + i]);
                accv[r4 * 4 + i] = fmaf(av[i], wv, accv[r4 * 4 + i]);
            }
        }
    }

    const float bqv = bq[t], bkv = bk[t], bvv = bv[t];
    #pragma unroll
    for (int r = 0; r < 32; ++r) {
        int row = row0 + r;
        qs[row * CDIM + t] = (accq[r] + bqv) * QK_SCALE;  // fold attention scale into q
        __hip_bfloat162 kv;
        kv.x = __float2bfloat16(acck[r] + bkv);
        kv.y = __float2bfloat16(accv[r] + bvv);
        kvs[row * CDIM + t] = kv;
    }
}

// ---------------- Kernel 2: per-query attention (32 neighbors, 8 heads) ----------------
// grid = NPTS blocks, 256 threads (= 8 heads x 32 dims). No k/v LDS staging:
// each neighbor row is read ONCE, coalesced (thread t = column t); k consumed
// immediately via a 32-lane head-group shuffle reduce, v stashed in registers.
__global__ __launch_bounds__(256, 4) void attn_kernel(
    const float* __restrict__ qs, const __hip_bfloat162* __restrict__ kvs,
    const int* __restrict__ index_1, const int* __restrict__ sort_idx,
    float* __restrict__ x)
{
    __shared__ float p_s[KNBR][NH + 1];
    __shared__ int nb_s[KNBR];

    const int n = blockIdx.x;
    const int t = threadIdx.x;
    const int h = t >> 5;                      // head (column group)

    const float qv = qs[n * CDIM + t];         // this thread's q element (scale folded)
    if (t < KNBR) nb_s[t] = index_1[n * KNBR + t];
    __syncthreads();

    // step 1: logits. Row j loaded coalesced (4B/lane: k and v packed).
    float vreg[KNBR];
    #pragma unroll
    for (int j = 0; j < KNBR; ++j) {
        const __hip_bfloat162 kv = kvs[(size_t)nb_s[j] * CDIM + t];
        vreg[j] = __bfloat162float(kv.y);      // stash v for step 2 (zero reloads)
        float prod = qv * __bfloat162float(kv.x);
        #pragma unroll
        for (int off = 16; off > 0; off >>= 1) // reduce over 32 dims of head h
            prod += __shfl_xor(prod, off);
        if ((t & 31) == 0) p_s[j][h] = prod;
    }
    __syncthreads();

    // softmax over j per head: thread (j = t&31, hh = t>>5)
    {
        const int j = t & 31, hh = t >> 5;
        const float a = p_s[j][hh];
        float m = a;
        #pragma unroll
        for (int off = 16; off > 0; off >>= 1)
            m = fmaxf(m, __shfl_xor(m, off));
        const float e = __expf(a - m);
        float ssum = e;
        #pragma unroll
        for (int off = 16; off > 0; off >>= 1)
            ssum += __shfl_xor(ssum, off);
        p_s[j][hh] = e / ssum;
    }
    __syncthreads();

    // step 2: out[h][d] from registers (v already resident)
    float o = 0.f;
    #pragma unroll
    for (int j = 0; j < KNBR; ++j)
        o = fmaf(p_s[j][h], vreg[j], o);

    const int orig = sort_idx[n];              // uniform -> scalar load
    x[orig * CDIM + t] = o;                    // coalesced scatter row
}

// ---------------- Kernel 3: output projection (x aliased with out is safe per-block) ----
// grid = NPTS/32 blocks, 256 threads. Thread = 2 cols x 16 rows.
__global__ __launch_bounds__(256, 2) void proj_kernel(
    const float* x, const float* __restrict__ Wp, const float* __restrict__ bp,
    float* out)
{
    __shared__ float in_t[CDIM][40];
    const int t = threadIdx.x;
    const int row0 = blockIdx.x * 32;

    #pragma unroll 8
    for (int r = 0; r < 32; ++r)
        in_t[t][r] = x[(row0 + r) * CDIM + t];
    __syncthreads();

    const int c0 = (t & 127) * 2;
    const int rh = (t >> 7) * 16;              // wave-uniform (waves 0,1 -> 0; 2,3 -> 16)
    float acc0[16], acc1[16];
    #pragma unroll
    for (int r = 0; r < 16; ++r) { acc0[r] = 0.f; acc1[r] = 0.f; }

    #pragma unroll 2
    for (int c = 0; c < CDIM; ++c) {
        const float2 w = *reinterpret_cast<const float2*>(&Wp[c * CDIM + c0]);
        #pragma unroll
        for (int r4 = 0; r4 < 4; ++r4) {
            const float4 a = *reinterpret_cast<const float4*>(&in_t[c][rh + r4 * 4]); // broadcast
            const float av[4] = {a.x, a.y, a.z, a.w};
            #pragma unroll
            for (int i = 0; i < 4; ++i) {
                acc0[r4 * 4 + i] = fmaf(av[i], w.x, acc0[r4 * 4 + i]);
                acc1[r4 * 4 + i] = fmaf(av[i], w.y, acc1[r4 * 4 + i]);
            }
        }
    }

    const float b0 = bp[c0], b1 = bp[c0 + 1];
    #pragma unroll
    for (int r = 0; r < 16; ++r) {
        float2 o;
        o.x = acc0[r] + b0;
        o.y = acc1[r] + b1;
        *reinterpret_cast<float2*>(&out[(row0 + rh + r) * CDIM + c0]) = o;
    }
}

extern "C" void kernel_launch(void* const* d_in, const int* in_sizes, int n_in,
                              void* d_out, int out_size, void* d_ws, size_t ws_size,
                              hipStream_t stream) {
    const float* qf  = (const float*)d_in[0];
    const float* Wq  = (const float*)d_in[1];
    const float* bq  = (const float*)d_in[2];
    const float* Wk  = (const float*)d_in[3];
    const float* bk  = (const float*)d_in[4];
    const float* Wv  = (const float*)d_in[5];
    const float* bv  = (const float*)d_in[6];
    const float* Wp  = (const float*)d_in[7];
    const float* bp  = (const float*)d_in[8];
    // d_in[9] = index_0 (unused: segment m -> query m/32 by construction)
    const int* index_1  = (const int*)d_in[10];
    const int* sort_idx = (const int*)d_in[11];
    float* out = (float*)d_out;

    float* qs = (float*)d_ws;                              // N*C f32, sorted order
    __hip_bfloat162* kvs = (__hip_bfloat162*)(qs + (size_t)NPTS * CDIM); // N*C bf16 (k,v) pairs

    qkv_kernel<<<NPTS / 32, 256, 0, stream>>>(qf, Wq, bq, Wk, bk, Wv, bv, sort_idx, qs, kvs);
    attn_kernel<<<NPTS, 256, 0, stream>>>(qs, kvs, index_1, sort_idx, out);
    proj_kernel<<<NPTS / 32, 256, 0, stream>>>(out, Wp, bp, out);
}

// Round 4
// 299.590 us; speedup vs baseline: 2.2273x; 2.2273x over previous
//
#include <hip/hip_runtime.h>
#include <hip/hip_bf16.h>

#define NPTS 40000
#define KNBR 32
#define CDIM 256
#define NH 8
#define HD 32

static constexpr float QK_SCALE = 0.17677669529663687f; // 32^-0.5

typedef __attribute__((ext_vector_type(8))) __bf16 bf16x8;
typedef __attribute__((ext_vector_type(4))) float f32x4;

static __device__ __forceinline__ unsigned short bfbits(float f) {
    __bf16 h = (__bf16)f;                      // RNE convert
    union { __bf16 b; unsigned short u; } c; c.b = h;
    return c.u;
}

// ---------------- Kernel 0: transpose+convert W (256x256 f32) -> Wt[n][k] bf16 ----------
__global__ __launch_bounds__(256) void wtr_kernel(
    const float* __restrict__ Wq, const float* __restrict__ Wk, const float* __restrict__ Wv,
    __bf16* __restrict__ WtQ, __bf16* __restrict__ WtK, __bf16* __restrict__ WtV)
{
    __shared__ float tile[32][33];
    const float* W = (blockIdx.z == 0) ? Wq : (blockIdx.z == 1) ? Wk : Wv;
    __bf16* Wt = (blockIdx.z == 0) ? WtQ : (blockIdx.z == 1) ? WtK : WtV;
    const int t = threadIdx.x;
    const int k0 = blockIdx.x * 32, n0 = blockIdx.y * 32;
    const int r = t >> 3, c4 = (t & 7) * 4;
    const float4 v = *reinterpret_cast<const float4*>(&W[(k0 + r) * CDIM + n0 + c4]);
    tile[r][c4 + 0] = v.x; tile[r][c4 + 1] = v.y;
    tile[r][c4 + 2] = v.z; tile[r][c4 + 3] = v.w;
    __syncthreads();
    __bf16 o[4];
    #pragma unroll
    for (int i = 0; i < 4; ++i) o[i] = (__bf16)tile[c4 + i][r];
    *reinterpret_cast<ulong1*>(&Wt[(n0 + r) * CDIM + k0 + c4]) =
        *reinterpret_cast<ulong1*>(o);
}

// ---------------- Kernel 1: QKV projection via MFMA, sort-gathered rows -----------------
// grid = 1250, block 256 (4 waves). Block: 32 sorted rows x 256 cols x {q,k,v}.
// Wave w owns cols [w*64, w*64+64). No LDS: A-frags from global f32 rows (cvt to bf16),
// B-frags straight 16B bf16 loads from pre-transposed Wt.
__global__ __launch_bounds__(256, 2) void qkv_kernel(
    const float* __restrict__ X,
    const __bf16* __restrict__ WtQ, const __bf16* __restrict__ WtK, const __bf16* __restrict__ WtV,
    const float* __restrict__ bq, const float* __restrict__ bk, const float* __restrict__ bv,
    const int* __restrict__ sort_idx,
    float* __restrict__ qs, unsigned int* __restrict__ kvs)
{
    const int t = threadIdx.x;
    const int w = t >> 6, l = t & 63;
    const int row0 = blockIdx.x * 32;
    const int lr = l & 15;                     // frag row/col within 16
    const int lk = (l >> 4) * 8;               // frag k-offset (8 contiguous)
    const int nbase = w * 64;

    const int rA0 = sort_idx[row0 + lr];
    const int rA1 = sort_idx[row0 + 16 + lr];
    const float* pA0 = X + (size_t)rA0 * CDIM + lk;
    const float* pA1 = X + (size_t)rA1 * CDIM + lk;
    const __bf16* Wts[3] = {WtQ, WtK, WtV};

    f32x4 acc[3][2][4];
    #pragma unroll
    for (int s = 0; s < 3; ++s)
        #pragma unroll
        for (int mf = 0; mf < 2; ++mf)
            #pragma unroll
            for (int nf = 0; nf < 4; ++nf)
                acc[s][mf][nf] = (f32x4){0.f, 0.f, 0.f, 0.f};

    #pragma unroll 2
    for (int k0 = 0; k0 < CDIM; k0 += 32) {
        bf16x8 a[2];
        {
            const float4 f0 = *reinterpret_cast<const float4*>(pA0 + k0);
            const float4 f1 = *reinterpret_cast<const float4*>(pA0 + k0 + 4);
            a[0][0] = (__bf16)f0.x; a[0][1] = (__bf16)f0.y; a[0][2] = (__bf16)f0.z; a[0][3] = (__bf16)f0.w;
            a[0][4] = (__bf16)f1.x; a[0][5] = (__bf16)f1.y; a[0][6] = (__bf16)f1.z; a[0][7] = (__bf16)f1.w;
            const float4 g0 = *reinterpret_cast<const float4*>(pA1 + k0);
            const float4 g1 = *reinterpret_cast<const float4*>(pA1 + k0 + 4);
            a[1][0] = (__bf16)g0.x; a[1][1] = (__bf16)g0.y; a[1][2] = (__bf16)g0.z; a[1][3] = (__bf16)g0.w;
            a[1][4] = (__bf16)g1.x; a[1][5] = (__bf16)g1.y; a[1][6] = (__bf16)g1.z; a[1][7] = (__bf16)g1.w;
        }
        #pragma unroll
        for (int s = 0; s < 3; ++s) {
            #pragma unroll
            for (int nf = 0; nf < 4; ++nf) {
                const bf16x8 b = *reinterpret_cast<const bf16x8*>(
                    Wts[s] + (size_t)(nbase + nf * 16 + lr) * CDIM + k0 + lk);
                acc[s][0][nf] = __builtin_amdgcn_mfma_f32_16x16x32_bf16(a[0], b, acc[s][0][nf], 0, 0, 0);
                acc[s][1][nf] = __builtin_amdgcn_mfma_f32_16x16x32_bf16(a[1], b, acc[s][1][nf], 0, 0, 0);
            }
        }
    }

    // epilogue: C/D mapping col = lane&15, row = (lane>>4)*4 + i
    const int rbase = (l >> 4) * 4;
    #pragma unroll
    for (int nf = 0; nf < 4; ++nf) {
        const int col = nbase + nf * 16 + lr;
        const float bqv = bq[col], bkv = bk[col], bvv = bv[col];
        #pragma unroll
        for (int mf = 0; mf < 2; ++mf) {
            #pragma unroll
            for (int i = 0; i < 4; ++i) {
                const int row = row0 + mf * 16 + rbase + i;
                qs[row * CDIM + col] = (acc[0][mf][nf][i] + bqv) * QK_SCALE;
                const unsigned int kb = bfbits(acc[1][mf][nf][i] + bkv);
                const unsigned int vb = bfbits(acc[2][mf][nf][i] + bvv);
                kvs[row * CDIM + col] = kb | (vb << 16);
            }
        }
    }
}

// ---------------- Kernel 2: attention — one query per WAVE, online softmax -------------
// Lane l owns cols l*4..l*4+3 (head h = l>>3). Per neighbor: one uint4 gather
// (4 packed (k,v) bf16 pairs), 3-step shfl_xor dot-reduce over 8 lanes, online
// softmax update. No LDS, no syncthreads, no per-thread arrays.
// Output written to xbuf (bf16, sorted->orig scatter) — NOT d_out (avoids the
// read/write race proj would otherwise have with in-place aliasing).
__global__ __launch_bounds__(256, 4) void attn_kernel(
    const float* __restrict__ qs, const unsigned int* __restrict__ kvs,
    const int* __restrict__ index_1, const int* __restrict__ sort_idx,
    __bf16* __restrict__ xbuf)
{
    const int wv = threadIdx.x >> 6;
    const int n = blockIdx.x * 4 + wv;         // query (sorted order)
    const int l = threadIdx.x & 63;
    const int c0 = l * 4;

    const float4 qv = *reinterpret_cast<const float4*>(&qs[(size_t)n * CDIM + c0]);
    float m = -INFINITY, lsum = 0.f;
    float o0 = 0.f, o1 = 0.f, o2 = 0.f, o3 = 0.f;
    const int* idx = index_1 + (size_t)n * KNBR;

    #pragma unroll 8
    for (int j = 0; j < KNBR; ++j) {
        const int nb = idx[j];                 // wave-uniform -> s_load
        const uint4 kv = *reinterpret_cast<const uint4*>(&kvs[(size_t)nb * CDIM + c0]);
        const float k0 = __uint_as_float(kv.x << 16);
        const float v0 = __uint_as_float(kv.x & 0xffff0000u);
        const float k1 = __uint_as_float(kv.y << 16);
        const float v1 = __uint_as_float(kv.y & 0xffff0000u);
        const float k2 = __uint_as_float(kv.z << 16);
        const float v2 = __uint_as_float(kv.z & 0xffff0000u);
        const float k3 = __uint_as_float(kv.w << 16);
        const float v3 = __uint_as_float(kv.w & 0xffff0000u);
        float dot = qv.x * k0;
        dot = fmaf(qv.y, k1, dot);
        dot = fmaf(qv.z, k2, dot);
        dot = fmaf(qv.w, k3, dot);
        dot += __shfl_xor(dot, 1);             // reduce over the 8 lanes of this head
        dot += __shfl_xor(dot, 2);
        dot += __shfl_xor(dot, 4);
        const float mn = fmaxf(m, dot);
        const float corr = __expf(m - mn);     // 0 on first iter (m = -inf)
        const float e = __expf(dot - mn);
        lsum = fmaf(lsum, corr, e);
        o0 = fmaf(o0, corr, e * v0);
        o1 = fmaf(o1, corr, e * v1);
        o2 = fmaf(o2, corr, e * v2);
        o3 = fmaf(o3, corr, e * v3);
        m = mn;
    }

    const float inv = 1.f / lsum;
    const int orig = sort_idx[n];              // wave-uniform -> s_load
    __bf16 o[4];
    o[0] = (__bf16)(o0 * inv); o[1] = (__bf16)(o1 * inv);
    o[2] = (__bf16)(o2 * inv); o[3] = (__bf16)(o3 * inv);
    *reinterpret_cast<ulong1*>(&xbuf[(size_t)orig * CDIM + c0]) =
        *reinterpret_cast<ulong1*>(o);         // coalesced 8B/lane
}

// ---------------- Kernel 3: output projection via MFMA (xbuf bf16 -> d_out f32) --------
__global__ __launch_bounds__(256, 2) void proj_kernel(
    const __bf16* __restrict__ X, const __bf16* __restrict__ WtP, const float* __restrict__ bp,
    float* __restrict__ out)
{
    const int t = threadIdx.x;
    const int w = t >> 6, l = t & 63;
    const int row0 = blockIdx.x * 32;
    const int lr = l & 15;
    const int lk = (l >> 4) * 8;
    const int nbase = w * 64;

    const __bf16* pA0 = X + (size_t)(row0 + lr) * CDIM + lk;
    const __bf16* pA1 = X + (size_t)(row0 + 16 + lr) * CDIM + lk;

    f32x4 acc[2][4];
    #pragma unroll
    for (int mf = 0; mf < 2; ++mf)
        #pragma unroll
        for (int nf = 0; nf < 4; ++nf)
            acc[mf][nf] = (f32x4){0.f, 0.f, 0.f, 0.f};

    #pragma unroll 2
    for (int k0 = 0; k0 < CDIM; k0 += 32) {
        const bf16x8 a0 = *reinterpret_cast<const bf16x8*>(pA0 + k0);  // direct 16B bf16 loads
        const bf16x8 a1 = *reinterpret_cast<const bf16x8*>(pA1 + k0);
        #pragma unroll
        for (int nf = 0; nf < 4; ++nf) {
            const bf16x8 b = *reinterpret_cast<const bf16x8*>(
                WtP + (size_t)(nbase + nf * 16 + lr) * CDIM + k0 + lk);
            acc[0][nf] = __builtin_amdgcn_mfma_f32_16x16x32_bf16(a0, b, acc[0][nf], 0, 0, 0);
            acc[1][nf] = __builtin_amdgcn_mfma_f32_16x16x32_bf16(a1, b, acc[1][nf], 0, 0, 0);
        }
    }

    const int rbase = (l >> 4) * 4;
    #pragma unroll
    for (int nf = 0; nf < 4; ++nf) {
        const int col = nbase + nf * 16 + lr;
        const float bpv = bp[col];
        #pragma unroll
        for (int mf = 0; mf < 2; ++mf) {
            #pragma unroll
            for (int i = 0; i < 4; ++i) {
                const int row = row0 + mf * 16 + rbase + i;
                out[row * CDIM + col] = acc[mf][nf][i] + bpv;
            }
        }
    }
}

extern "C" void kernel_launch(void* const* d_in, const int* in_sizes, int n_in,
                              void* d_out, int out_size, void* d_ws, size_t ws_size,
                              hipStream_t stream) {
    const float* qf  = (const float*)d_in[0];
    const float* Wq  = (const float*)d_in[1];
    const float* bq  = (const float*)d_in[2];
    const float* Wk  = (const float*)d_in[3];
    const float* bk  = (const float*)d_in[4];
    const float* Wv  = (const float*)d_in[5];
    const float* bv  = (const float*)d_in[6];
    const float* Wp  = (const float*)d_in[7];
    const float* bp  = (const float*)d_in[8];
    // d_in[9] = index_0 (unused: segment m -> query m/32 by construction)
    const int* index_1  = (const int*)d_in[10];
    const int* sort_idx = (const int*)d_in[11];
    float* out = (float*)d_out;

    float* qs = (float*)d_ws;                                  // 40.96 MB f32, sorted
    unsigned int* kvs = (unsigned int*)(qs + (size_t)NPTS * CDIM); // 40.96 MB packed bf16 (k,v)
    __bf16* xbuf = (__bf16*)(kvs + (size_t)NPTS * CDIM);       // 20.48 MB bf16 attn output
    __bf16* WtQ = xbuf + (size_t)NPTS * CDIM;                  // 4 x 128 KB bf16 Wt
    __bf16* WtK = WtQ + CDIM * CDIM;
    __bf16* WtV = WtK + CDIM * CDIM;
    __bf16* WtP = WtV + CDIM * CDIM;
    // total ws use: 40.96 + 40.96 + 20.48 + 0.5 MB = 102.9 MB

    wtr_kernel<<<dim3(8, 8, 3), 256, 0, stream>>>(Wq, Wk, Wv, WtQ, WtK, WtV);
    wtr_kernel<<<dim3(8, 8, 1), 256, 0, stream>>>(Wp, Wp, Wp, WtP, WtP, WtP);
    qkv_kernel<<<NPTS / 32, 256, 0, stream>>>(qf, WtQ, WtK, WtV, bq, bk, bv, sort_idx, qs, kvs);
    attn_kernel<<<NPTS / 4, 256, 0, stream>>>(qs, kvs, index_1, sort_idx, xbuf);
    proj_kernel<<<NPTS / 32, 256, 0, stream>>>(xbuf, WtP, bp, out);
}